// Round 12
// baseline (106.128 us; speedup 1.0000x reference)
//
#include <hip/hip_runtime.h>
#include <math.h>

#define TL 2048
#define PI_D 3.14159265358979323846

typedef __attribute__((ext_vector_type(8))) short short8v;
typedef __attribute__((ext_vector_type(4))) float float4v;

#define BROW 4144          // extended replica row length (elems)
#define BSTRIDE 3168       // B replica row stride in LDS (bytes)
#define A_BYTES 32768      // A half-K tile in LDS

__device__ __forceinline__ unsigned short bf16_rne(float f) {
  unsigned u = __float_as_uint(f);
  return (unsigned short)((u + 0x7FFFu + ((u >> 16) & 1u)) >> 16);
}

// tap value k[d], d = idx - 2047
__device__ __forceinline__ float tap_val(int idx, double beta, double wv) {
  int d = idx - 2047;
  double x = PI_D * (double)d / 6144.0 - beta;
  if (fabs(x) < 1e-9) return 1.0f;
  double c = wv * (cos(x) / sin(x));
  if (d & 1) c = -c;
  return (float)c;
}

// ---------------------------------------------------------------------------
// K1 (340 blocks) — verbatim round-10 (proven):
//  b<64: frame-kernel bf16 shift replicas (extended rows).
//  b in [64,80): kerC exclusive tap prefix.  b in [80,336): tsh conv.
//  b in [336,340): Whl pack.
// ---------------------------------------------------------------------------
__global__ __launch_bounds__(256) void build_shift_k(const float* __restrict__ shifts,
                                                     const float* __restrict__ time_in,
                                                     const float* __restrict__ w_pos,
                                                     float* __restrict__ kerC,
                                                     unsigned short* __restrict__ BFrep,
                                                     unsigned short* __restrict__ tsh_b,
                                                     unsigned short* __restrict__ Whl) {
  __shared__ __align__(16) unsigned char sm1[17408];
  __shared__ float wsum[4];
  int b = blockIdx.x;
  int tid = threadIdx.x;
  if (b < 80) {
    float* kf = (float*)sm1;  // 4104 floats
    double s;
    if (b < 64) s = (double)b * (1.0 / 63.0) * (2048.0 / 3.0);
    else        s = (double)shifts[b - 64] * (2048.0 / 3.0);
    double beta = PI_D * s / 3073.0;
    double y = 3072.0 * s / 3073.0;
    double r = y - rint(y);
    double wv = -sin(2.0 * PI_D * r) / 6144.0;
    for (int idx = tid; idx < 4104; idx += 256)
      kf[idx] = (idx < 4095) ? tap_val(idx, beta, wv) : 0.0f;
    __syncthreads();
    if (b < 64) {
      int sr = tid >> 5, lane5 = tid & 31;
#pragma unroll
      for (int it = 0; it < 17; ++it) {
        int m = lane5 + (it << 5);
        if (m < 518) {
          unsigned short out8[8];
#pragma unroll
          for (int i = 0; i < 8; ++i) {
            int arg = 4095 - (8 * m + i) + sr;
            out8[i] = (arg >= 0) ? bf16_rne(kf[arg]) : (unsigned short)0;
          }
          *(short8v*)(BFrep + ((size_t)(b * 8 + sr)) * BROW + 8 * m) = *(short8v*)out8;
        }
      }
    } else {
      float s0 = 0.f;
      int base = tid * 16;
#pragma unroll
      for (int i = 0; i < 16; ++i) s0 += kf[base + i];
      int lane = tid & 63;
      float v = s0;
#pragma unroll
      for (int d = 1; d < 64; d <<= 1) {
        float o = __shfl_up(v, (unsigned)d, 64);
        if (lane >= d) v += o;
      }
      if (lane == 63) wsum[tid >> 6] = v;
      __syncthreads();
      float woff = 0.f;
      for (int k = 0; k < (tid >> 6); ++k) woff += wsum[k];
      float run = v + woff - s0;
      float* crow = kerC + (b - 64) * 4096;
#pragma unroll
      for (int i = 0; i < 16; ++i) {
        crow[base + i] = run;
        run += kf[base + i];
      }
    }
  } else if (b < 336) {
    // shift_time, u-split
    int idx = b - 80;
    int p = idx >> 4, tile = idx & 15;
    int t0 = tile * 128;
    float* a = (float*)sm1;                  // 2048 f
    float* kw = (float*)(sm1 + 8192);        // 2176 f
    float* partial = (float*)(sm1 + 16896);  // 128 f
    double s = (double)shifts[p] * (2048.0 / 3.0);
    double beta = PI_D * s / 3073.0;
    double y = 3072.0 * s / 3073.0;
    double r = y - rint(y);
    double wv = -sin(2.0 * PI_D * r) / 6144.0;
    for (int i = tid; i < 2048; i += 256) a[i] = time_in[p * 2048 + i];
    for (int i = tid; i < 2175; i += 256) kw[i] = tap_val(t0 + i, beta, wv);
    __syncthreads();
    int tl = tid & 127, uh = tid >> 7;
    int base = tl + 2047 - (uh << 10);
    int u0 = uh << 10;
    float acc = 0.f;
#pragma unroll 8
    for (int u2 = 0; u2 < 1024; ++u2) acc = fmaf(a[u0 + u2], kw[base - u2], acc);
    __syncthreads();
    if (uh == 1) partial[tl] = acc;
    __syncthreads();
    if (uh == 0) {
      acc += partial[tl];
      tsh_b[p * 2048 + t0 + tl] = bf16_rne(acc);
    }
  } else {
    // Whl pack
    int c0 = (b - 336) * 1024 + tid * 4;
#pragma unroll
    for (int k2 = 0; k2 < 4; ++k2) {
      int c = c0 + k2;
      int sel = c & 1, g = (c >> 1) & 3, p16v = (c >> 3) & 15;
      int kc = (c >> 7) & 7, ct = c >> 10;
      const float* wrow = w_pos + (ct * 16 + p16v) * 256 + kc * 32 + g * 8;
      short8v ov;
#pragma unroll
      for (int i = 0; i < 8; ++i) {
        float vv = wrow[i];
        unsigned short hb = bf16_rne(vv);
        if (sel == 0) ov[i] = (short)hb;
        else {
          float hf = __uint_as_float(((unsigned)hb) << 16);
          ov[i] = (short)bf16_rne(vv - hf);
        }
      }
      *(short8v*)(Whl + (size_t)c * 8) = ov;
    }
  }
}

// ---------------------------------------------------------------------------
// K2 (784 blocks x 512 thr) — verbatim round-10 (proven):
//  bx<512: expT barrier-free MFMA (K-split halves -> expTh).
//  [512,768): pos MFMA.  [768,784): s-branch MLP.
// ---------------------------------------------------------------------------
__global__ __launch_bounds__(512, 4) void fused3_k(const unsigned short* __restrict__ tsh_b,
                                                   const unsigned short* __restrict__ BFrep,
                                                   float* __restrict__ expTh,
                                                   const unsigned short* __restrict__ Whl,
                                                   const float* __restrict__ b_pos,
                                                   float* __restrict__ pos,
                                                   const float* __restrict__ shape,
                                                   const float* __restrict__ w_layers,
                                                   const float* __restrict__ b_layers,
                                                   float* __restrict__ s64) {
  __shared__ __align__(16) unsigned char smem[A_BYTES + 8 * BSTRIDE];  // 58112 B
  int bx = blockIdx.x;
  int tid = threadIdx.x;
  if (bx < 512) {
    int j = bx & 63;
    int kh = (bx >> 6) & 1;
    int tQ = bx >> 7;
    int l = tid & 63, w = tid >> 6;
    int p16 = l & 15, g = l >> 4;
    int srep = p16 & 7, hb = p16 >> 3;
    const unsigned short* grow = BFrep + (size_t)j * 8 * BROW;
    int z_lo = 1536 - 512 * tQ + 1024 * kh;

#pragma unroll
    for (int it = 0; it < 4; ++it) {
      int c = tid + (it << 9);
      int pp = c >> 7, m = c & 127;
      short8v v = *(const short8v*)(tsh_b + pp * 2048 + kh * 1024 + (m << 3));
      int dst = ((pp << 11) + (m << 4)) ^ ((pp & 7) << 4);
      *(short8v*)(smem + dst) = v;
    }
    {
      int sr = tid >> 6, lane6 = tid & 63;
      const unsigned short* srcrow = grow + sr * BROW + z_lo;
      unsigned char* dstrow = smem + A_BYTES + sr * BSTRIDE;
#pragma unroll
      for (int it = 0; it < 4; ++it) {
        int m = lane6 + (it << 6);
        if (m < 197) {
          short8v v = *(const short8v*)(srcrow + (m << 3));
          *(short8v*)(dstrow + (m << 4)) = v;
        }
      }
    }
    __syncthreads();

    float4v acc[4];
#pragma unroll
    for (int i = 0; i < 4; ++i) acc[i] = (float4v){0.f, 0.f, 0.f, 0.f};
    int bBbase = A_BYTES + srep * BSTRIDE + 1024 - (w << 7) - (hb << 4) + (g << 4);
    short8v W2 = *(const short8v*)(smem + bBbase - 64);
    short8v W3 = *(const short8v*)(smem + bBbase - 96);
#pragma unroll 4
    for (int kc = 0; kc < 32; ++kc) {
      int ao = ((p16 << 11) + (kc << 6) + (g << 4)) ^ ((p16 & 7) << 4);
      short8v a = *(const short8v*)(smem + ao);
      int fb = bBbase + (kc << 6);
      short8v W0 = *(const short8v*)(smem + fb);
      short8v W1 = *(const short8v*)(smem + fb - 32);
      acc[0] = __builtin_amdgcn_mfma_f32_16x16x32_bf16(a, W0, acc[0], 0, 0, 0);
      acc[1] = __builtin_amdgcn_mfma_f32_16x16x32_bf16(a, W1, acc[1], 0, 0, 0);
      acc[2] = __builtin_amdgcn_mfma_f32_16x16x32_bf16(a, W2, acc[2], 0, 0, 0);
      acc[3] = __builtin_amdgcn_mfma_f32_16x16x32_bf16(a, W3, acc[3], 0, 0, 0);
      W2 = W0;
      W3 = W1;
    }
    float* dstp = expTh + (size_t)kh * (16 * 64 * 2048);
    int tcb = 512 * tQ + 64 * w + p16;
#pragma unroll
    for (int ct = 0; ct < 4; ++ct) {
#pragma unroll
      for (int rr = 0; rr < 4; ++rr) {
        int prow = (g << 2) + rr;
        dstp[(size_t)(prow * 64 + j) * TL + tcb + (ct << 4)] = acc[ct][rr];
      }
    }
  } else if (bx < 768) {
    int l = tid & 63, w = tid >> 6;
    int p16 = l & 15, g = l >> 4;
    int T0 = (bx - 512) * 128 + w * 16;

    float ttv = (float)(T0 + p16) * (32768.0f / 32767.0f);
    float4v acc0 = {0.f, 0.f, 0.f, 0.f};
    float4v acc1 = {0.f, 0.f, 0.f, 0.f};
    const short8v* Wt = (const short8v*)Whl;
    int fbase = (p16 << 3) + (g << 1);
#pragma unroll
    for (int kc = 0; kc < 8; ++kc) {
      short8v bh0 = Wt[(kc << 7) + fbase];
      short8v bl0 = Wt[(kc << 7) + fbase + 1];
      short8v bh1 = Wt[1024 + (kc << 7) + fbase];
      short8v bl1 = Wt[1024 + (kc << 7) + fbase + 1];
      short8v ahi, alo;
#pragma unroll
      for (int i = 0; i < 8; ++i) {
        int f = kc * 32 + g * 8 + i;
        float fr = 1e-5f + (float)f * ((0.5f - 1e-5f) / 255.0f);
        float rev = ttv * (0.5f * fr);
        float sv = __builtin_amdgcn_sinf(__builtin_amdgcn_fractf(rev));
        unsigned short hbit = bf16_rne(sv);
        float hf = __uint_as_float(((unsigned)hbit) << 16);
        ahi[i] = (short)hbit;
        alo[i] = (short)bf16_rne(sv - hf);
      }
      acc0 = __builtin_amdgcn_mfma_f32_16x16x32_bf16(ahi, bh0, acc0, 0, 0, 0);
      acc1 = __builtin_amdgcn_mfma_f32_16x16x32_bf16(ahi, bh1, acc1, 0, 0, 0);
      acc0 = __builtin_amdgcn_mfma_f32_16x16x32_bf16(ahi, bl0, acc0, 0, 0, 0);
      acc1 = __builtin_amdgcn_mfma_f32_16x16x32_bf16(ahi, bl1, acc1, 0, 0, 0);
      acc0 = __builtin_amdgcn_mfma_f32_16x16x32_bf16(alo, bh0, acc0, 0, 0, 0);
      acc1 = __builtin_amdgcn_mfma_f32_16x16x32_bf16(alo, bh1, acc1, 0, 0, 0);
    }
    float bp0 = b_pos[p16], bp1 = b_pos[16 + p16];
    float4v o0, o1;
#pragma unroll
    for (int rr = 0; rr < 4; ++rr) {
      o0[rr] = acc0[rr] + bp0;
      o1[rr] = acc1[rr] + bp1;
    }
    int Tr = T0 + g * 4;
    *(float4v*)(pos + (size_t)p16 * 32768 + Tr) = o0;
    *(float4v*)(pos + (size_t)(16 + p16) * 32768 + Tr) = o1;
  } else {
    float(*sA)[33] = (float(*)[33])(smem);
    float(*sB)[33] = (float(*)[33])(smem + 8448);
    float(*W)[33] = (float(*)[33])(smem + 16896);
    float* bb = (float*)(smem + 25344);
    int p = bx - 768;
    for (int idx = tid; idx < 2048; idx += 512) {
      int c = idx >> 6, f = idx & 63;
      sA[f][c] = shape[p * 2048 + idx];
    }
    int c = tid & 31, fg = tid >> 5;
    for (int ll = 0; ll < 4; ++ll) {
      for (int idx = tid; idx < 1024; idx += 512) W[idx >> 5][idx & 31] = w_layers[ll * 1024 + idx];
      if (tid < 32) bb[tid] = b_layers[ll * 32 + tid];
      __syncthreads();
      float(*cur)[33] = (ll & 1) ? sB : sA;
      float(*nxt)[33] = (ll & 1) ? sA : sB;
#pragma unroll
      for (int i = 0; i < 4; ++i) {
        int f = fg * 4 + i;
        float acc = cur[f][c] + bb[c];
#pragma unroll
        for (int k = 0; k < 32; ++k) acc = fmaf(fmaxf(cur[f][k], 0.f), W[c][k], acc);
        nxt[f][c] = acc;
      }
      __syncthreads();
    }
    for (int idx = tid; idx < 2048; idx += 512) {
      int cc = idx >> 6, f = idx & 63;
      s64[p * 2048 + idx] = fmaxf(sA[f][cc], 0.f);
    }
  }
}

// ---------------------------------------------------------------------------
// K3 (512 blocks): env (fused mask, K-half sum) into LDS with 2 halo columns,
// then final output for this tile's 1024 T. env never touches HBM.
//  kcl[i] = kerC[p][tC-1+i], i in [0,2112). Column tt (t = tC-1+tt):
//    Ct = kcl[tt], mv(jj) = kcl[tt+2046-jj] - Ct   (max idx 65+2046=2111 OK)
//  Main cols tt=tl+1 use the EXACT R10 env2 layout; halo tt in {0,65} via a
//  jj-split pass. Halo col 0 unused when tile==0; col 65 unused when tile==31.
// ---------------------------------------------------------------------------
__global__ __launch_bounds__(256) void envfinal2_k(const float* __restrict__ energy,
                                                   const float* __restrict__ props,
                                                   const float* __restrict__ expTh,
                                                   const float* __restrict__ kerC,
                                                   const float* __restrict__ pos,
                                                   const float* __restrict__ s64,
                                                   float* __restrict__ out) {
  __shared__ float Et[64][36];
  __shared__ float K[32];
  __shared__ float kcl[2112];
  __shared__ float env_s[32][68];
  __shared__ float hpart[2][32][4];
  int p = blockIdx.x >> 5, tile = blockIdx.x & 31;
  int tid = threadIdx.x;
  int tC = tile * 64, tCm1 = tC - 1;
  for (int i = tid; i < 2048; i += 256) Et[i & 63][i >> 6] = energy[p * 2048 + i];
  const float* crow = kerC + p * 4096;
  for (int i = tid; i < 2112; i += 256) {
    int gi = tCm1 + i;  // max = 1984-1+2111 = 4094 < 4096
    kcl[i] = (gi >= 0) ? crow[gi] : 0.f;
  }
  if (tid < 32) {
    float mass = props[(p * 32 + tid) * 2];
    float fric = props[(p * 32 + tid) * 2 + 1];
    K[tid] = fric / (2.0f * mass);
  }
  __syncthreads();
  int tl = tid & 63, cg = tid >> 6;
  // --- main 64 columns (identical math/layout to R10 env2) ---
  {
    float acc[8];
    float kk[8];
#pragma unroll
    for (int i = 0; i < 8; ++i) acc[i] = 0.f;
#pragma unroll
    for (int i = 0; i < 8; ++i) kk[i] = K[cg * 8 + i];
    float Ct = kcl[tl + 1];
    const float* xrow0 = expTh + (size_t)p * 64 * TL + (tC + tl);
    const float* xrow1 = xrow0 + (size_t)16 * 64 * TL;
    for (int jj = 0; jj < 64; ++jj) {
      float x = xrow0[jj * TL] + xrow1[jj * TL];
      float mv = kcl[tl + 1 + 2046 - jj] - Ct;
      float4v e0 = *(const float4v*)(&Et[jj][cg * 8]);
      float4v e1 = *(const float4v*)(&Et[jj][cg * 8 + 4]);
#pragma unroll
      for (int cc = 0; cc < 4; ++cc)
        acc[cc] = fmaf(e0[cc] * mv, __expf(-kk[cc] * x), acc[cc]);
#pragma unroll
      for (int cc = 0; cc < 4; ++cc)
        acc[4 + cc] = fmaf(e1[cc] * mv, __expf(-kk[4 + cc] * x), acc[4 + cc]);
    }
#pragma unroll
    for (int cc = 0; cc < 8; ++cc) env_s[cg * 8 + cc][tl + 1] = acc[cc];
  }
  // --- 2 halo columns: tid -> (hcol, c, js), each sums 16 jj ---
  {
    int hcol = tid >> 7, rest = tid & 127;
    int c = rest >> 2, js = rest & 3;
    int t = tCm1 + hcol * 65;              // -1 .. 2048
    int tcl2 = min(max(t, 0), 2047);       // clamp for expTh read (unused cols)
    int ttc = hcol * 65;
    float Ct = kcl[ttc];
    float kc_ = K[c];
    const float* x0 = expTh + (size_t)p * 64 * TL + tcl2;
    const float* x1 = x0 + (size_t)16 * 64 * TL;
    float a = 0.f;
    int j0 = js * 16;
#pragma unroll
    for (int jj = j0; jj < j0 + 16; ++jj) {
      float x = x0[jj * TL] + x1[jj * TL];
      float mv = kcl[ttc + 2046 - jj] - Ct;
      a = fmaf(Et[jj][c] * mv, __expf(-kc_ * x), a);
    }
    hpart[hcol][c][js] = a;
  }
  __syncthreads();
  if (tid < 64) {
    int hcol = tid >> 5, c = tid & 31;
    env_s[c][hcol * 65] =
        hpart[hcol][c][0] + hpart[hcol][c][1] + hpart[hcol][c][2] + hpart[hcol][c][3];
  }
  __syncthreads();
  // --- final for T in [tile*1024, tile*1024+1024) ---
  int T0 = tile * 1024;
  const float* srow = s64 + p * 2048;
#pragma unroll
  for (int q = 0; q < 4; ++q) {
    int T = T0 + q * 256 + tid;
    float ft = (float)T + 0.5f;
    float ce = fminf(fmaxf(ft * 0.0625f - 0.5f, 0.f), 2047.f);
    int ie = (int)ce;
    int ie1 = min(ie + 1, 2047);
    float we = ce - (float)ie;
    int iel = ie - tCm1, iel1 = ie1 - tCm1;  // in [0,65]
    float cs = fminf(fmaxf(ft * (1.0f / 512.0f) - 0.5f, 0.f), 63.f);
    int is0 = (int)cs;
    int is1 = min(is0 + 1, 63);
    float wsv = cs - (float)is0;
    float acc = 0.f;
    for (int c = 0; c < 32; ++c) {
      float pv = pos[(size_t)c * 32768 + T];
      float ev = fmaxf(env_s[c][iel] * (1.f - we) + env_s[c][iel1] * we, 0.f);
      float sv = srow[c * 64 + is0] * (1.f - wsv) + srow[c * 64 + is1] * wsv;
      acc += pv * sv * ev;
    }
    out[(size_t)p * 32768 + T] = acc;
  }
}

extern "C" void kernel_launch(void* const* d_in, const int* in_sizes, int n_in,
                              void* d_out, int out_size, void* d_ws, size_t ws_size,
                              hipStream_t stream) {
  const float* time_in  = (const float*)d_in[0];
  const float* shifts   = (const float*)d_in[1];
  const float* energy   = (const float*)d_in[2];
  const float* shape    = (const float*)d_in[3];
  const float* props    = (const float*)d_in[4];
  const float* w_pos    = (const float*)d_in[5];
  const float* b_pos    = (const float*)d_in[6];
  const float* w_layers = (const float*)d_in[7];
  const float* b_layers = (const float*)d_in[8];

  float* ws = (float*)d_ws;
  float* kerC = ws;                                          // 65536 f
  unsigned short* BFrep = (unsigned short*)(ws + 65536);     // 64*8*4144 u16
  unsigned short* tsh_b = (unsigned short*)(ws + 1126400);   // 32768 u16
  float* expTh = ws + 1142784;                               // 2 x 2097152 f
  float* pos  = ws + 5337088;                                // 1048576 f
  float* s64  = ws + 6385664;                                // 32768 f
  unsigned short* Whl = (unsigned short*)(ws + 6418432);     // 32768 u16
  float* out  = (float*)d_out;

  hipLaunchKernelGGL(build_shift_k, dim3(340), dim3(256), 0, stream,
                     shifts, time_in, w_pos, kerC, BFrep, tsh_b, Whl);
  hipLaunchKernelGGL(fused3_k, dim3(784), dim3(512), 0, stream, tsh_b, BFrep, expTh,
                     Whl, b_pos, pos, shape, w_layers, b_layers, s64);
  hipLaunchKernelGGL(envfinal2_k, dim3(512), dim3(256), 0, stream,
                     energy, props, expTh, kerC, pos, s64, out);
}

// Round 13
// 86.186 us; speedup vs baseline: 1.2314x; 1.2314x over previous
//
#include <hip/hip_runtime.h>
#include <math.h>

#define TL 2048
#define PI_D 3.14159265358979323846

typedef __attribute__((ext_vector_type(8))) short short8v;
typedef __attribute__((ext_vector_type(4))) float float4v;

#define BROW 4144          // extended replica row length (elems)
#define BSTRIDE 3168       // B replica row stride in LDS (bytes)
#define A_BYTES 32768      // A half-K tile in LDS
#define RVS 2180           // reversed-tap replica row stride (floats)

__device__ __forceinline__ unsigned short bf16_rne(float f) {
  unsigned u = __float_as_uint(f);
  return (unsigned short)((u + 0x7FFFu + ((u >> 16) & 1u)) >> 16);
}

// tap value k[d], d = idx - 2047
__device__ __forceinline__ float tap_val(int idx, double beta, double wv) {
  int d = idx - 2047;
  double x = PI_D * (double)d / 6144.0 - beta;
  if (fabs(x) < 1e-9) return 1.0f;
  double c = wv * (cos(x) / sin(x));
  if (d & 1) c = -c;
  return (float)c;
}

// ---------------------------------------------------------------------------
// K1 (340 blocks):
//  b<64: frame-kernel bf16 shift replicas (extended rows).
//  b in [64,80): kerC exclusive tap prefix.
//  b in [80,336): tsh conv — VECTORIZED: reversed-tap 4-replica layout so
//    kw[base-u2] becomes ascending contiguous -> b128 pairs; 2 indep accs.
//  b in [336,340): Whl pack.
// ---------------------------------------------------------------------------
__global__ __launch_bounds__(256) void build_shift_k(const float* __restrict__ shifts,
                                                     const float* __restrict__ time_in,
                                                     const float* __restrict__ w_pos,
                                                     float* __restrict__ kerC,
                                                     unsigned short* __restrict__ BFrep,
                                                     unsigned short* __restrict__ tsh_b,
                                                     unsigned short* __restrict__ Whl) {
  __shared__ __align__(16) unsigned char sm1[43600];
  __shared__ float wsum[4];
  int b = blockIdx.x;
  int tid = threadIdx.x;
  if (b < 80) {
    float* kf = (float*)sm1;  // 4104 floats
    double s;
    if (b < 64) s = (double)b * (1.0 / 63.0) * (2048.0 / 3.0);
    else        s = (double)shifts[b - 64] * (2048.0 / 3.0);
    double beta = PI_D * s / 3073.0;
    double y = 3072.0 * s / 3073.0;
    double r = y - rint(y);
    double wv = -sin(2.0 * PI_D * r) / 6144.0;
    for (int idx = tid; idx < 4104; idx += 256)
      kf[idx] = (idx < 4095) ? tap_val(idx, beta, wv) : 0.0f;
    __syncthreads();
    if (b < 64) {
      int sr = tid >> 5, lane5 = tid & 31;
#pragma unroll
      for (int it = 0; it < 17; ++it) {
        int m = lane5 + (it << 5);
        if (m < 518) {
          unsigned short out8[8];
#pragma unroll
          for (int i = 0; i < 8; ++i) {
            int arg = 4095 - (8 * m + i) + sr;
            out8[i] = (arg >= 0) ? bf16_rne(kf[arg]) : (unsigned short)0;
          }
          *(short8v*)(BFrep + ((size_t)(b * 8 + sr)) * BROW + 8 * m) = *(short8v*)out8;
        }
      }
    } else {
      float s0 = 0.f;
      int base = tid * 16;
#pragma unroll
      for (int i = 0; i < 16; ++i) s0 += kf[base + i];
      int lane = tid & 63;
      float v = s0;
#pragma unroll
      for (int d = 1; d < 64; d <<= 1) {
        float o = __shfl_up(v, (unsigned)d, 64);
        if (lane >= d) v += o;
      }
      if (lane == 63) wsum[tid >> 6] = v;
      __syncthreads();
      float woff = 0.f;
      for (int k = 0; k < (tid >> 6); ++k) woff += wsum[k];
      float run = v + woff - s0;
      float* crow = kerC + (b - 64) * 4096;
#pragma unroll
      for (int i = 0; i < 16; ++i) {
        crow[base + i] = run;
        run += kf[base + i];
      }
    }
  } else if (b < 336) {
    // tsh conv, u-split 2x, vectorized reversed-tap reads
    int idx = b - 80;
    int p = idx >> 4, tile = idx & 15;
    int t0 = tile * 128;
    float* a = (float*)sm1;                    // 2048 f @ 0
    float* Rv = (float*)(sm1 + 8192);          // 4 x 2180 f
    float* partial = (float*)(sm1 + 43072);    // 128 f
    double s = (double)shifts[p] * (2048.0 / 3.0);
    double beta = PI_D * s / 3073.0;
    double y = 3072.0 * s / 3073.0;
    double r = y - rint(y);
    double wv = -sin(2.0 * PI_D * r) / 6144.0;
    for (int i = tid; i < 2048; i += 256) a[i] = time_in[p * 2048 + i];
    // replica 0: Rv[i] = kw[2175-i] = tap(t0+2175-i), 0 at tap idx >= 4095
    for (int i = tid; i < 2180; i += 256) {
      int ti = t0 + 2175 - i;
      Rv[i] = (ti >= 0 && ti < 4095) ? tap_val(ti, beta, wv) : 0.f;
    }
    __syncthreads();
    // replicas 1..3: Rv_s[j] = Rv[j+s] (0 beyond)
    for (int i = tid; i < 3 * RVS; i += 256) {
      int s2 = 1 + i / RVS, j = i - (s2 - 1) * RVS;
      int src = j + s2;
      Rv[s2 * RVS + j] = (src < 2176) ? Rv[src] : 0.f;
    }
    __syncthreads();
    int tl = tid & 127, uh = tid >> 7;
    int u0 = uh << 10;
    int c0 = 128 - tl + u0;
    int srep = c0 & 3;
    int idx0 = c0 - srep;
    const float* Rrow = Rv + srep * RVS + idx0;
    const float* ap = a + u0;
    float acc0 = 0.f, acc1 = 0.f;
#pragma unroll 8
    for (int u2 = 0; u2 < 1024; u2 += 8) {
      float4v av0 = *(const float4v*)(ap + u2);
      float4v kv0 = *(const float4v*)(Rrow + u2);
      float4v av1 = *(const float4v*)(ap + u2 + 4);
      float4v kv1 = *(const float4v*)(Rrow + u2 + 4);
#pragma unroll
      for (int q = 0; q < 4; ++q) acc0 = fmaf(av0[q], kv0[q], acc0);
#pragma unroll
      for (int q = 0; q < 4; ++q) acc1 = fmaf(av1[q], kv1[q], acc1);
    }
    float acc = acc0 + acc1;
    __syncthreads();
    if (uh == 1) partial[tl] = acc;
    __syncthreads();
    if (uh == 0) {
      acc += partial[tl];
      tsh_b[p * 2048 + t0 + tl] = bf16_rne(acc);
    }
  } else {
    // Whl pack
    int c0 = (b - 336) * 1024 + tid * 4;
#pragma unroll
    for (int k2 = 0; k2 < 4; ++k2) {
      int c = c0 + k2;
      int sel = c & 1, g = (c >> 1) & 3, p16v = (c >> 3) & 15;
      int kc = (c >> 7) & 7, ct = c >> 10;
      const float* wrow = w_pos + (ct * 16 + p16v) * 256 + kc * 32 + g * 8;
      short8v ov;
#pragma unroll
      for (int i = 0; i < 8; ++i) {
        float vv = wrow[i];
        unsigned short hb = bf16_rne(vv);
        if (sel == 0) ov[i] = (short)hb;
        else {
          float hf = __uint_as_float(((unsigned)hb) << 16);
          ov[i] = (short)bf16_rne(vv - hf);
        }
      }
      *(short8v*)(Whl + (size_t)c * 8) = ov;
    }
  }
}

// ---------------------------------------------------------------------------
// K2 (784 blocks x 512 thr) — verbatim round-10 (proven):
//  bx<512: expT barrier-free MFMA (K-split halves -> expTh).
//  [512,768): pos MFMA.  [768,784): s-branch MLP.
// ---------------------------------------------------------------------------
__global__ __launch_bounds__(512, 4) void fused3_k(const unsigned short* __restrict__ tsh_b,
                                                   const unsigned short* __restrict__ BFrep,
                                                   float* __restrict__ expTh,
                                                   const unsigned short* __restrict__ Whl,
                                                   const float* __restrict__ b_pos,
                                                   float* __restrict__ pos,
                                                   const float* __restrict__ shape,
                                                   const float* __restrict__ w_layers,
                                                   const float* __restrict__ b_layers,
                                                   float* __restrict__ s64) {
  __shared__ __align__(16) unsigned char smem[A_BYTES + 8 * BSTRIDE];  // 58112 B
  int bx = blockIdx.x;
  int tid = threadIdx.x;
  if (bx < 512) {
    int j = bx & 63;
    int kh = (bx >> 6) & 1;
    int tQ = bx >> 7;
    int l = tid & 63, w = tid >> 6;
    int p16 = l & 15, g = l >> 4;
    int srep = p16 & 7, hb = p16 >> 3;
    const unsigned short* grow = BFrep + (size_t)j * 8 * BROW;
    int z_lo = 1536 - 512 * tQ + 1024 * kh;

#pragma unroll
    for (int it = 0; it < 4; ++it) {
      int c = tid + (it << 9);
      int pp = c >> 7, m = c & 127;
      short8v v = *(const short8v*)(tsh_b + pp * 2048 + kh * 1024 + (m << 3));
      int dst = ((pp << 11) + (m << 4)) ^ ((pp & 7) << 4);
      *(short8v*)(smem + dst) = v;
    }
    {
      int sr = tid >> 6, lane6 = tid & 63;
      const unsigned short* srcrow = grow + sr * BROW + z_lo;
      unsigned char* dstrow = smem + A_BYTES + sr * BSTRIDE;
#pragma unroll
      for (int it = 0; it < 4; ++it) {
        int m = lane6 + (it << 6);
        if (m < 197) {
          short8v v = *(const short8v*)(srcrow + (m << 3));
          *(short8v*)(dstrow + (m << 4)) = v;
        }
      }
    }
    __syncthreads();

    float4v acc[4];
#pragma unroll
    for (int i = 0; i < 4; ++i) acc[i] = (float4v){0.f, 0.f, 0.f, 0.f};
    int bBbase = A_BYTES + srep * BSTRIDE + 1024 - (w << 7) - (hb << 4) + (g << 4);
    short8v W2 = *(const short8v*)(smem + bBbase - 64);
    short8v W3 = *(const short8v*)(smem + bBbase - 96);
#pragma unroll 4
    for (int kc = 0; kc < 32; ++kc) {
      int ao = ((p16 << 11) + (kc << 6) + (g << 4)) ^ ((p16 & 7) << 4);
      short8v a = *(const short8v*)(smem + ao);
      int fb = bBbase + (kc << 6);
      short8v W0 = *(const short8v*)(smem + fb);
      short8v W1 = *(const short8v*)(smem + fb - 32);
      acc[0] = __builtin_amdgcn_mfma_f32_16x16x32_bf16(a, W0, acc[0], 0, 0, 0);
      acc[1] = __builtin_amdgcn_mfma_f32_16x16x32_bf16(a, W1, acc[1], 0, 0, 0);
      acc[2] = __builtin_amdgcn_mfma_f32_16x16x32_bf16(a, W2, acc[2], 0, 0, 0);
      acc[3] = __builtin_amdgcn_mfma_f32_16x16x32_bf16(a, W3, acc[3], 0, 0, 0);
      W2 = W0;
      W3 = W1;
    }
    float* dstp = expTh + (size_t)kh * (16 * 64 * 2048);
    int tcb = 512 * tQ + 64 * w + p16;
#pragma unroll
    for (int ct = 0; ct < 4; ++ct) {
#pragma unroll
      for (int rr = 0; rr < 4; ++rr) {
        int prow = (g << 2) + rr;
        dstp[(size_t)(prow * 64 + j) * TL + tcb + (ct << 4)] = acc[ct][rr];
      }
    }
  } else if (bx < 768) {
    int l = tid & 63, w = tid >> 6;
    int p16 = l & 15, g = l >> 4;
    int T0 = (bx - 512) * 128 + w * 16;

    float ttv = (float)(T0 + p16) * (32768.0f / 32767.0f);
    float4v acc0 = {0.f, 0.f, 0.f, 0.f};
    float4v acc1 = {0.f, 0.f, 0.f, 0.f};
    const short8v* Wt = (const short8v*)Whl;
    int fbase = (p16 << 3) + (g << 1);
#pragma unroll
    for (int kc = 0; kc < 8; ++kc) {
      short8v bh0 = Wt[(kc << 7) + fbase];
      short8v bl0 = Wt[(kc << 7) + fbase + 1];
      short8v bh1 = Wt[1024 + (kc << 7) + fbase];
      short8v bl1 = Wt[1024 + (kc << 7) + fbase + 1];
      short8v ahi, alo;
#pragma unroll
      for (int i = 0; i < 8; ++i) {
        int f = kc * 32 + g * 8 + i;
        float fr = 1e-5f + (float)f * ((0.5f - 1e-5f) / 255.0f);
        float rev = ttv * (0.5f * fr);
        float sv = __builtin_amdgcn_sinf(__builtin_amdgcn_fractf(rev));
        unsigned short hbit = bf16_rne(sv);
        float hf = __uint_as_float(((unsigned)hbit) << 16);
        ahi[i] = (short)hbit;
        alo[i] = (short)bf16_rne(sv - hf);
      }
      acc0 = __builtin_amdgcn_mfma_f32_16x16x32_bf16(ahi, bh0, acc0, 0, 0, 0);
      acc1 = __builtin_amdgcn_mfma_f32_16x16x32_bf16(ahi, bh1, acc1, 0, 0, 0);
      acc0 = __builtin_amdgcn_mfma_f32_16x16x32_bf16(ahi, bl0, acc0, 0, 0, 0);
      acc1 = __builtin_amdgcn_mfma_f32_16x16x32_bf16(ahi, bl1, acc1, 0, 0, 0);
      acc0 = __builtin_amdgcn_mfma_f32_16x16x32_bf16(alo, bh0, acc0, 0, 0, 0);
      acc1 = __builtin_amdgcn_mfma_f32_16x16x32_bf16(alo, bh1, acc1, 0, 0, 0);
    }
    float bp0 = b_pos[p16], bp1 = b_pos[16 + p16];
    float4v o0, o1;
#pragma unroll
    for (int rr = 0; rr < 4; ++rr) {
      o0[rr] = acc0[rr] + bp0;
      o1[rr] = acc1[rr] + bp1;
    }
    int Tr = T0 + g * 4;
    *(float4v*)(pos + (size_t)p16 * 32768 + Tr) = o0;
    *(float4v*)(pos + (size_t)(16 + p16) * 32768 + Tr) = o1;
  } else {
    float(*sA)[33] = (float(*)[33])(smem);
    float(*sB)[33] = (float(*)[33])(smem + 8448);
    float(*W)[33] = (float(*)[33])(smem + 16896);
    float* bb = (float*)(smem + 25344);
    int p = bx - 768;
    for (int idx = tid; idx < 2048; idx += 512) {
      int c = idx >> 6, f = idx & 63;
      sA[f][c] = shape[p * 2048 + idx];
    }
    int c = tid & 31, fg = tid >> 5;
    for (int ll = 0; ll < 4; ++ll) {
      for (int idx = tid; idx < 1024; idx += 512) W[idx >> 5][idx & 31] = w_layers[ll * 1024 + idx];
      if (tid < 32) bb[tid] = b_layers[ll * 32 + tid];
      __syncthreads();
      float(*cur)[33] = (ll & 1) ? sB : sA;
      float(*nxt)[33] = (ll & 1) ? sA : sB;
#pragma unroll
      for (int i = 0; i < 4; ++i) {
        int f = fg * 4 + i;
        float acc = cur[f][c] + bb[c];
#pragma unroll
        for (int k = 0; k < 32; ++k) acc = fmaf(fmaxf(cur[f][k], 0.f), W[c][k], acc);
        nxt[f][c] = acc;
      }
      __syncthreads();
    }
    for (int idx = tid; idx < 2048; idx += 512) {
      int cc = idx >> 6, f = idx & 63;
      s64[p * 2048 + idx] = fmaxf(sA[f][cc], 0.f);
    }
  }
}

// ---------------------------------------------------------------------------
// K3 (512 blocks x 512 thr): env fused with mask; 8 c-groups x 4 channels
// (double the TLP of R10's 256-thr version, same math & layout).
// ---------------------------------------------------------------------------
__global__ __launch_bounds__(512) void env2_k(const float* __restrict__ energy,
                                              const float* __restrict__ props,
                                              const float* __restrict__ expTh,
                                              const float* __restrict__ kerC,
                                              float* __restrict__ env) {
  int p = blockIdx.x >> 5, tile = blockIdx.x & 31;
  int tid = threadIdx.x;
  int tl = tid & 63;
  int cg = tid >> 6;  // 0..7, 4 channels each
  int tC = tile * 64;
  int t = tC + tl;
  __shared__ float Et[64][36];
  __shared__ float K[32];
  __shared__ float kcl[2112];
  for (int i = tid; i < 2048; i += 512) Et[i & 63][i >> 6] = energy[p * 2048 + i];
  const float* crow = kerC + p * 4096;
  for (int i = tid; i < 2110; i += 512) kcl[i] = crow[tC + i];
  if (tid < 32) {
    float mass = props[(p * 32 + tid) * 2];
    float fric = props[(p * 32 + tid) * 2 + 1];
    K[tid] = fric / (2.0f * mass);
  }
  __syncthreads();
  float acc[4];
  float kk[4];
#pragma unroll
  for (int i = 0; i < 4; ++i) acc[i] = 0.f;
#pragma unroll
  for (int i = 0; i < 4; ++i) kk[i] = K[cg * 4 + i];
  float Ct = kcl[tl];
  const float* xrow0 = expTh + (size_t)p * 64 * TL + t;
  const float* xrow1 = xrow0 + (size_t)16 * 64 * TL;
  for (int jj = 0; jj < 64; ++jj) {
    float x = xrow0[jj * TL] + xrow1[jj * TL];
    float mv = kcl[tl + 2046 - jj] - Ct;
    float4v e0 = *(const float4v*)(&Et[jj][cg * 4]);
#pragma unroll
    for (int cc = 0; cc < 4; ++cc)
      acc[cc] = fmaf(e0[cc] * mv, __expf(-kk[cc] * x), acc[cc]);
  }
#pragma unroll
  for (int cc = 0; cc < 4; ++cc)
    env[(size_t)(p * 32 + cg * 4 + cc) * TL + t] = acc[cc];
}

// ---------------------------------------------------------------------------
// K4 (2048 blocks): final (R10 verbatim)
// ---------------------------------------------------------------------------
__global__ __launch_bounds__(256) void final_k(const float* __restrict__ pos,
                                               const float* __restrict__ s64,
                                               const float* __restrict__ env,
                                               float* __restrict__ out) {
  int gid = blockIdx.x * 256 + threadIdx.x;
  int p = gid >> 15, T = gid & 32767;
  float ft = (float)T + 0.5f;
  float ce = fminf(fmaxf(ft * 0.0625f - 0.5f, 0.f), 2047.f);
  int ie = (int)ce;
  int ie1 = min(ie + 1, 2047);
  float we = ce - (float)ie;
  float cs = fminf(fmaxf(ft * (1.0f / 512.0f) - 0.5f, 0.f), 63.f);
  int is0 = (int)cs;
  int is1 = min(is0 + 1, 63);
  float ws = cs - (float)is0;
  const float* erow = env + (size_t)p * 32 * TL;
  const float* srow = s64 + p * 32 * 64;
  float acc = 0.f;
  for (int c = 0; c < 32; ++c) {
    float pv = pos[(size_t)c * 32768 + T];
    float ev = fmaxf(erow[c * TL + ie] * (1.f - we) + erow[c * TL + ie1] * we, 0.f);
    float sv = srow[c * 64 + is0] * (1.f - ws) + srow[c * 64 + is1] * ws;
    acc += pv * sv * ev;
  }
  out[gid] = acc;
}

extern "C" void kernel_launch(void* const* d_in, const int* in_sizes, int n_in,
                              void* d_out, int out_size, void* d_ws, size_t ws_size,
                              hipStream_t stream) {
  const float* time_in  = (const float*)d_in[0];
  const float* shifts   = (const float*)d_in[1];
  const float* energy   = (const float*)d_in[2];
  const float* shape    = (const float*)d_in[3];
  const float* props    = (const float*)d_in[4];
  const float* w_pos    = (const float*)d_in[5];
  const float* b_pos    = (const float*)d_in[6];
  const float* w_layers = (const float*)d_in[7];
  const float* b_layers = (const float*)d_in[8];

  float* ws = (float*)d_ws;
  float* kerC = ws;                                          // 65536 f
  unsigned short* BFrep = (unsigned short*)(ws + 65536);     // 64*8*4144 u16
  unsigned short* tsh_b = (unsigned short*)(ws + 1126400);   // 32768 u16
  float* expTh = ws + 1142784;                               // 2 x 2097152 f
  float* pos  = ws + 5337088;                                // 1048576 f
  float* s64  = ws + 6385664;                                // 32768 f
  unsigned short* Whl = (unsigned short*)(ws + 6418432);     // 32768 u16
  float* env  = ws + 6434816;                                // 1048576 f
  float* out  = (float*)d_out;

  hipLaunchKernelGGL(build_shift_k, dim3(340), dim3(256), 0, stream,
                     shifts, time_in, w_pos, kerC, BFrep, tsh_b, Whl);
  hipLaunchKernelGGL(fused3_k, dim3(784), dim3(512), 0, stream, tsh_b, BFrep, expTh,
                     Whl, b_pos, pos, shape, w_layers, b_layers, s64);
  hipLaunchKernelGGL(env2_k, dim3(512), dim3(512), 0, stream, energy, props, expTh, kerC, env);
  hipLaunchKernelGGL(final_k, dim3(2048), dim3(256), 0, stream, pos, s64, env, out);
}